// Round 13
// baseline (8242.909 us; speedup 1.0000x reference)
//
#include <hip/hip_runtime.h>
#include <hip/hip_bf16.h>

#define TT 512
#define BB 64
#define DD 2048
#define LL 4
#define VV 64

typedef unsigned short u16;
typedef unsigned int u32;
typedef unsigned long long u64;
typedef __attribute__((ext_vector_type(8))) short s16x8;
typedef __attribute__((ext_vector_type(4))) float f32x4;

#define MFMA(a, b, c) __builtin_amdgcn_mfma_f32_16x16x32_bf16((a), (b), (c), 0, 0, 0)

#define GL(gp, lp)                                                        \
  __builtin_amdgcn_global_load_lds(                                       \
      (const __attribute__((address_space(1))) void*)(gp),                \
      (__attribute__((address_space(3))) void*)(lp), 16, 0, 0)

__device__ inline u16 f2b(float f) {
  u32 u = __builtin_bit_cast(u32, f);
  u32 r = (u + 0x7fffu + ((u >> 16) & 1u)) >> 16;
  return (u16)r;
}
__device__ inline float b2f(u16 b) {
  u32 u = ((u32)b) << 16;
  return __builtin_bit_cast(float, u);
}

__global__ __launch_bounds__(256) void convert_w(const float* __restrict__ src,
                                                 u16* __restrict__ dst, size_t n4) {
  size_t i = (size_t)blockIdx.x * 256 + threadIdx.x;
  size_t stride = (size_t)gridDim.x * 256;
  for (size_t j = i; j < n4; j += stride) {
    float4 f = ((const float4*)src)[j];
    ushort4 o;
    o.x = f2b(f.x); o.y = f2b(f.y); o.z = f2b(f.z); o.w = f2b(f.w);
    ((ushort4*)dst)[j] = o;
  }
}

__global__ __launch_bounds__(256) void convert_woT(const float* __restrict__ Wout,
                                                   u16* __restrict__ WoT) {
  int g = blockIdx.x * 256 + threadIdx.x;
  int v = g >> 11, k = g & 2047;
  WoT[(size_t)v * DD + k] = f2b(Wout[(size_t)k * VV + v]);
}

__global__ __launch_bounds__(256) void transpose_ids(const int* __restrict__ ids,
                                                     int* __restrict__ idsT) {
  int g = blockIdx.x * 256 + threadIdx.x;
  int b = g >> 9, t = g & 511;
  idsT[t * BB + b] = ids[b * TT + t];
}

// Persistent: 256 blocks x 512 threads, 1 block/CU. Block -> (layer, 32 cols).
// 8 waves split K; wave-private LDS dbuf staging via global_load_lds, counted
// vmcnt. Weights pinned in regs. State: 4-ring, AGENT write-through stores,
// acquire-inv every 4 steps. Barrier: wave0-only flag scan publishing the
// epoch to LDS; other waves spin on LDS (no per-round block syncs). Out-proj
// of step t runs AFTER barrier t (overlaps next step's staging issue).
__global__ __launch_bounds__(512, 2)
void persist(const int* __restrict__ idsT, const int* __restrict__ slen,
             const float* __restrict__ bxp, const float* __restrict__ bhp,
             const u16* __restrict__ embb,
             const u16* __restrict__ Wxb, const u16* __restrict__ Whb,
             const u16* __restrict__ WoT, const float* __restrict__ bout,
             u16* hb, float* __restrict__ out, int* flags) {
  const int tid = threadIdx.x, bid = blockIdx.x;
  const int l = bid >> 6;
  const int col0 = (bid & 63) << 5;
  const int w = tid >> 6, lane = tid & 63;
  const int lr = lane & 15, q = lane >> 4;
  const size_t HSZ = (size_t)LL * BB * DD;

  // ---- weight frags: [ctile][chunk], k = w*256 + j*32 + q*8 ----
  s16x8 wx[2][8], wh[2][8];
#pragma unroll
  for (int c = 0; c < 2; ++c) {
    const int ncol = col0 + (c << 4) + lr;
    const u16* p0 = Wxb + ((size_t)l * DD + ncol) * DD + (w << 8) + (q << 3);
    const u16* p1 = Whb + ((size_t)l * DD + ncol) * DD + (w << 8) + (q << 3);
#pragma unroll
    for (int j = 0; j < 8; ++j) {
      wx[c][j] = *(const s16x8*)(p0 + (j << 5));
      wh[c][j] = *(const s16x8*)(p1 + (j << 5));
    }
  }
#pragma unroll
  for (int c = 0; c < 2; ++c)
#pragma unroll
    for (int j = 0; j < 8; ++j) {
      asm("" : "+v"(wx[c][j]));
      asm("" : "+v"(wh[c][j]));
    }

  // ---- out-proj: 4 batch x 4 vocab per block ----
  const int opo = tid >> 5, ln32 = tid & 31;
  const int opb = ((bid >> 4) << 2) + (opo >> 2);
  const int opv = ((bid & 15) << 2) + (opo & 3);
  const float boutv = bout[opv];

  // ---- reduce mapping: thread -> (row, col-quad) ----
  const int rm = tid >> 3;
  const int rng = (tid & 7) << 2;
  const int qcol = col0 + rng;
  float qb[4];
#pragma unroll
  for (int e = 0; e < 4; ++e)
    qb[e] = bxp[l * DD + qcol + e] + bhp[l * DD + qcol + e];
  const int qlen = slen[rm];

  // ---- staging lane decomposition (source pre-permuted; rule #21) ----
  const int lrow = lane >> 2;
  const int lelem = ((lane & 3) ^ ((lane >> 3) & 3)) << 3;
  const int fx = lr * 32 + ((q ^ ((lr >> 1) & 3)) << 3);

  // LDS: stg (8 waves x 2 slots x 8KB = 128KB) UNION part[8][64][36] (72KB)
  __shared__ __align__(16) u16 stg[65536];
  float* part = (float*)stg;
  __shared__ int sids[64];
  __shared__ int ldsEp;

  u16* wslot = stg + (w << 13);
  volatile int* vep = (volatile int*)&ldsEp;

  if (tid == 0) ldsEp = 0;
  __syncthreads();

  for (int t = 0; t < TT; ++t) {
    const u16* Hp = hb + (size_t)((t + 3) & 3) * HSZ;
    u16* Hc = hb + (size_t)(t & 3) * HSZ;

    // ---------- compute step t ----------
    if (l == 0) {
      if (tid < BB) sids[tid] = idsT[t * BB + tid];
      __syncthreads();
    }
    const int kw = (w << 8) + lelem;
    const u16* hb0 = Hp + (size_t)l * BB * DD + kw;
    const u16 *px0, *px1, *px2, *px3;
    if (l == 0) {
      px0 = embb + (size_t)sids[lrow] * DD + kw;
      px1 = embb + (size_t)sids[16 + lrow] * DD + kw;
      px2 = embb + (size_t)sids[32 + lrow] * DD + kw;
      px3 = embb + (size_t)sids[48 + lrow] * DD + kw;
    } else {
      const u16* xb0 = Hp + (size_t)(l - 1) * BB * DD + kw;
      px0 = xb0 + (size_t)lrow * DD;
      px1 = xb0 + (size_t)(16 + lrow) * DD;
      px2 = xb0 + (size_t)(32 + lrow) * DD;
      px3 = xb0 + (size_t)(48 + lrow) * DD;
    }
    const u16* ph0 = hb0 + (size_t)lrow * DD;
    const u16* ph1 = hb0 + (size_t)(16 + lrow) * DD;
    const u16* ph2 = hb0 + (size_t)(32 + lrow) * DD;
    const u16* ph3 = hb0 + (size_t)(48 + lrow) * DD;

#pragma unroll
    for (int c = 0; c < 2; ++c) {
      u16* d = wslot + (c << 12);
      GL(px0 + (c << 5), d);
      GL(px1 + (c << 5), d + 512);
      GL(px2 + (c << 5), d + 1024);
      GL(px3 + (c << 5), d + 1536);
      GL(ph0 + (c << 5), d + 2048);
      GL(ph1 + (c << 5), d + 2560);
      GL(ph2 + (c << 5), d + 3072);
      GL(ph3 + (c << 5), d + 3584);
    }

    f32x4 acc[2][4] = {{{0,0,0,0},{0,0,0,0},{0,0,0,0},{0,0,0,0}},
                       {{0,0,0,0},{0,0,0,0},{0,0,0,0},{0,0,0,0}}};
#pragma unroll
    for (int j = 0; j < 8; ++j) {
      if (j < 7) asm volatile("s_waitcnt vmcnt(8)" ::: "memory");
      else       asm volatile("s_waitcnt vmcnt(0)" ::: "memory");
      __builtin_amdgcn_sched_barrier(0);
      const u16* sb = wslot + ((j & 1) << 12);
      s16x8 ax0 = *(const s16x8*)(sb + fx);
      s16x8 ax1 = *(const s16x8*)(sb + 512 + fx);
      s16x8 ax2 = *(const s16x8*)(sb + 1024 + fx);
      s16x8 ax3 = *(const s16x8*)(sb + 1536 + fx);
      s16x8 ah0 = *(const s16x8*)(sb + 2048 + fx);
      s16x8 ah1 = *(const s16x8*)(sb + 2560 + fx);
      s16x8 ah2 = *(const s16x8*)(sb + 3072 + fx);
      s16x8 ah3 = *(const s16x8*)(sb + 3584 + fx);
      asm volatile("s_waitcnt lgkmcnt(0)" ::: "memory");
      __builtin_amdgcn_sched_barrier(0);
      if (j < 6) {
        u16* d = wslot + ((j & 1) << 12);
        const int co = (j + 2) << 5;
        GL(px0 + co, d);
        GL(px1 + co, d + 512);
        GL(px2 + co, d + 1024);
        GL(px3 + co, d + 1536);
        GL(ph0 + co, d + 2048);
        GL(ph1 + co, d + 2560);
        GL(ph2 + co, d + 3072);
        GL(ph3 + co, d + 3584);
      }
#pragma unroll
      for (int c = 0; c < 2; ++c) {
        acc[c][0] = MFMA(ax0, wx[c][j], acc[c][0]);
        acc[c][0] = MFMA(ah0, wh[c][j], acc[c][0]);
        acc[c][1] = MFMA(ax1, wx[c][j], acc[c][1]);
        acc[c][1] = MFMA(ah1, wh[c][j], acc[c][1]);
        acc[c][2] = MFMA(ax2, wx[c][j], acc[c][2]);
        acc[c][2] = MFMA(ah2, wh[c][j], acc[c][2]);
        acc[c][3] = MFMA(ax3, wx[c][j], acc[c][3]);
        acc[c][3] = MFMA(ah3, wh[c][j], acc[c][3]);
      }
    }

    __syncthreads();  // all waves done reading stg; part may overwrite
#pragma unroll
    for (int c = 0; c < 2; ++c)
#pragma unroll
      for (int mt = 0; mt < 4; ++mt)
#pragma unroll
        for (int i = 0; i < 4; ++i)
          part[((w << 6) + (mt << 4) + (q << 2) + i) * 36 + (c << 4) + lr] =
              acc[c][mt][i];
    __syncthreads();

    // 8-way K-combine + bias + tanh + mask + packed agent write-through store
    {
      f32x4 sum = {0, 0, 0, 0};
#pragma unroll
      for (int k2 = 0; k2 < 8; ++k2)
        sum += *(const f32x4*)&part[((k2 << 6) + rm) * 36 + rng];
      float h0 = tanhf(sum[0] + qb[0]);
      float h1 = tanhf(sum[1] + qb[1]);
      float h2 = tanhf(sum[2] + qb[2]);
      float h3 = tanhf(sum[3] + qb[3]);
      size_t idx = ((size_t)l * BB + rm) * DD + qcol;
      u64 pk = (u64)f2b(h0) | ((u64)f2b(h1) << 16) |
               ((u64)f2b(h2) << 32) | ((u64)f2b(h3) << 48);
      u64 val = (t < qlen) ? pk : *(const u64*)(Hp + idx);
      __hip_atomic_store((u64*)(Hc + idx), val, __ATOMIC_RELAXED,
                         __HIP_MEMORY_SCOPE_AGENT);
    }
    asm volatile("s_waitcnt vmcnt(0)" ::: "memory");
    __syncthreads();  // all waves' stores drained

    const int ep = t + 1;
    if (tid == 0)
      __hip_atomic_store(&flags[bid << 5], ep, __ATOMIC_RELAXED,
                         __HIP_MEMORY_SCOPE_AGENT);

    // ---------- barrier: wave0 scans, publishes epoch to LDS ----------
    if (w == 0) {
      const int i0 = lane << 5, i1 = (lane + 64) << 5;
      const int i2 = (lane + 128) << 5, i3 = (lane + 192) << 5;
      for (;;) {
        int a = __hip_atomic_load(&flags[i0], __ATOMIC_RELAXED,
                                  __HIP_MEMORY_SCOPE_AGENT);
        int b = __hip_atomic_load(&flags[i1], __ATOMIC_RELAXED,
                                  __HIP_MEMORY_SCOPE_AGENT);
        int c = __hip_atomic_load(&flags[i2], __ATOMIC_RELAXED,
                                  __HIP_MEMORY_SCOPE_AGENT);
        int d = __hip_atomic_load(&flags[i3], __ATOMIC_RELAXED,
                                  __HIP_MEMORY_SCOPE_AGENT);
        int m0 = a < b ? a : b;
        int m1 = c < d ? c : d;
        int mn = m0 < m1 ? m0 : m1;
        if (__all(mn >= ep)) break;
        __builtin_amdgcn_s_sleep(1);
      }
      // amortized acquire: one L1/L2 inv per 4 steps covers the 4-deep ring
      if ((ep & 3) == 0 && lane == 0)
        (void)__hip_atomic_load(&flags[0], __ATOMIC_ACQUIRE,
                                __HIP_MEMORY_SCOPE_AGENT);
      __builtin_amdgcn_sched_barrier(0);
      if (lane == 0) *vep = ep;   // publish AFTER inv
    }
    while (*vep < ep) __builtin_amdgcn_s_sleep(1);

    // ---------- out-proj for step t (state t now complete & visible) ----------
    {
      const u16* h3p = Hc + (size_t)3 * BB * DD;
      const u16* hp = h3p + (size_t)opb * DD + (ln32 << 6);
      const u16* wp = WoT + (size_t)opv * DD + (ln32 << 6);
      float sacc = 0.f;
#pragma unroll
      for (int j = 0; j < 64; j += 8) {
        s16x8 hv8 = *(const s16x8*)(hp + j);
        s16x8 wv8 = *(const s16x8*)(wp + j);
#pragma unroll
        for (int e = 0; e < 8; ++e)
          sacc = fmaf(b2f((u16)hv8[e]), b2f((u16)wv8[e]), sacc);
      }
#pragma unroll
      for (int d = 16; d > 0; d >>= 1) sacc += __shfl_xor(sacc, d, 64);
      if (ln32 == 0)
        out[((size_t)opb * TT + t) * VV + opv] = sacc + boutv;
    }
  }
}

extern "C" void kernel_launch(void* const* d_in, const int* in_sizes, int n_in,
                              void* d_out, int out_size, void* d_ws, size_t ws_size,
                              hipStream_t stream) {
  const int* ids = (const int*)d_in[0];
  const int* slen = (const int*)d_in[1];
  const float* emb = (const float*)d_in[2];
  const float* Wx = (const float*)d_in[3];
  const float* bx = (const float*)d_in[4];
  const float* Wh = (const float*)d_in[5];
  const float* bh = (const float*)d_in[6];
  const float* Wout = (const float*)d_in[7];
  const float* bout = (const float*)d_in[8];
  float* out = (float*)d_out;

  char* ws = (char*)d_ws;
  const size_t oW = (size_t)LL * DD * DD * 2;
  const size_t oWoT = (size_t)VV * DD * 2;
  const size_t oEmb = (size_t)VV * DD * 2;
  const size_t oHb = (size_t)LL * BB * DD * 2;
  u16* Wxb = (u16*)ws;
  u16* Whb = (u16*)(ws + oW);
  u16* WoT = (u16*)(ws + 2 * oW);
  u16* embb = (u16*)(ws + 2 * oW + oWoT);
  u16* hb = (u16*)(ws + 2 * oW + oWoT + oEmb);          // 4-ring state
  int* flags = (int*)(ws + 2 * oW + oWoT + oEmb + 4 * oHb);
  int* idsT = (int*)(ws + 2 * oW + oWoT + oEmb + 4 * oHb + 32768);

  hipMemsetAsync(ws + 2 * oW + oWoT + oEmb, 0, 4 * oHb + 32768, stream);

  const size_t n4 = (size_t)LL * DD * DD / 4;
  convert_w<<<dim3(4096), dim3(256), 0, stream>>>(Wx, Wxb, n4);
  convert_w<<<dim3(4096), dim3(256), 0, stream>>>(Wh, Whb, n4);
  convert_w<<<dim3(128), dim3(256), 0, stream>>>(emb, embb, (size_t)VV * DD / 4);
  convert_woT<<<dim3(512), dim3(256), 0, stream>>>(Wout, WoT);
  transpose_ids<<<dim3(128), dim3(256), 0, stream>>>(ids, idsT);

  void* kp[12];
  kp[0] = (void*)&idsT; kp[1] = (void*)&slen;
  kp[2] = (void*)&bx;   kp[3] = (void*)&bh;   kp[4] = (void*)&embb;
  kp[5] = (void*)&Wxb;  kp[6] = (void*)&Whb;  kp[7] = (void*)&WoT;
  kp[8] = (void*)&bout; kp[9] = (void*)&hb;   kp[10] = (void*)&out;
  kp[11] = (void*)&flags;
  hipLaunchCooperativeKernel((const void*)persist, dim3(256), dim3(512), kp, 0, stream);
}

// Round 14
// 7836.967 us; speedup vs baseline: 1.0518x; 1.0518x over previous
//
#include <hip/hip_runtime.h>
#include <hip/hip_bf16.h>

#define TT 512
#define BB 64
#define DD 2048
#define LL 4
#define VV 64

typedef unsigned short u16;
typedef unsigned int u32;
typedef unsigned long long u64;
typedef __attribute__((ext_vector_type(8))) short s16x8;
typedef __attribute__((ext_vector_type(4))) float f32x4;

#define MFMA(a, b, c) __builtin_amdgcn_mfma_f32_16x16x32_bf16((a), (b), (c), 0, 0, 0)

#define GL(gp, lp)                                                        \
  __builtin_amdgcn_global_load_lds(                                       \
      (const __attribute__((address_space(1))) void*)(gp),                \
      (__attribute__((address_space(3))) void*)(lp), 16, 0, 0)

__device__ inline u16 f2b(float f) {
  u32 u = __builtin_bit_cast(u32, f);
  u32 r = (u + 0x7fffu + ((u >> 16) & 1u)) >> 16;
  return (u16)r;
}
__device__ inline float b2f(u16 b) {
  u32 u = ((u32)b) << 16;
  return __builtin_bit_cast(float, u);
}

__global__ __launch_bounds__(256) void convert_w(const float* __restrict__ src,
                                                 u16* __restrict__ dst, size_t n4) {
  size_t i = (size_t)blockIdx.x * 256 + threadIdx.x;
  size_t stride = (size_t)gridDim.x * 256;
  for (size_t j = i; j < n4; j += stride) {
    float4 f = ((const float4*)src)[j];
    ushort4 o;
    o.x = f2b(f.x); o.y = f2b(f.y); o.z = f2b(f.z); o.w = f2b(f.w);
    ((ushort4*)dst)[j] = o;
  }
}

__global__ __launch_bounds__(256) void convert_woT(const float* __restrict__ Wout,
                                                   u16* __restrict__ WoT) {
  int g = blockIdx.x * 256 + threadIdx.x;
  int v = g >> 11, k = g & 2047;
  WoT[(size_t)v * DD + k] = f2b(Wout[(size_t)k * VV + v]);
}

__global__ __launch_bounds__(256) void transpose_ids(const int* __restrict__ ids,
                                                     int* __restrict__ idsT) {
  int g = blockIdx.x * 256 + threadIdx.x;
  int b = g >> 9, t = g & 511;
  idsT[t * BB + b] = ids[b * TT + t];
}

// Persistent: 256 blocks x 512 threads, 1 block/CU. Block -> (layer, 32 cols).
// LAYER-PIPELINED sync (no global lockstep): before step t, block gates on
//   group[l-1] >= t (x input), group[l] >= t (h input),
//   group[l+1] >= t-2 (ring-slot reuse safe; reader of state t-4 done).
// Layers lead each other by <=3 (L0 vs L3 <= 9). Layer-3 blocks also write
// their h3 slice to a 16-deep hist ring; all blocks lazily drain out-proj(s)
// for s < scanned group-3 min (backlog <= 9 < 16, overlap with peers' work).
// Weights pinned in regs; wave-private LDS dbuf staging (counted vmcnt);
// AGENT write-through state stores; acquire-inv every 4 own-steps.
__global__ __launch_bounds__(512, 2)
void persist(const int* __restrict__ idsT, const int* __restrict__ slen,
             const float* __restrict__ bxp, const float* __restrict__ bhp,
             const u16* __restrict__ embb,
             const u16* __restrict__ Wxb, const u16* __restrict__ Whb,
             const u16* __restrict__ WoT, const float* __restrict__ bout,
             u16* hb, u16* hist, float* __restrict__ out, int* flags) {
  const int tid = threadIdx.x, bid = blockIdx.x;
  const int l = bid >> 6;
  const int col0 = (bid & 63) << 5;
  const int w = tid >> 6, lane = tid & 63;
  const int lr = lane & 15, q = lane >> 4;
  const size_t HSZ = (size_t)LL * BB * DD;
  const size_t H3SZ = (size_t)BB * DD;

  // ---- weight frags: [ctile][chunk], k = w*256 + j*32 + q*8 ----
  s16x8 wx[2][8], wh[2][8];
#pragma unroll
  for (int c = 0; c < 2; ++c) {
    const int ncol = col0 + (c << 4) + lr;
    const u16* p0 = Wxb + ((size_t)l * DD + ncol) * DD + (w << 8) + (q << 3);
    const u16* p1 = Whb + ((size_t)l * DD + ncol) * DD + (w << 8) + (q << 3);
#pragma unroll
    for (int j = 0; j < 8; ++j) {
      wx[c][j] = *(const s16x8*)(p0 + (j << 5));
      wh[c][j] = *(const s16x8*)(p1 + (j << 5));
    }
  }
#pragma unroll
  for (int c = 0; c < 2; ++c)
#pragma unroll
    for (int j = 0; j < 8; ++j) {
      asm("" : "+v"(wx[c][j]));
      asm("" : "+v"(wh[c][j]));
    }

  // ---- out-proj: 4 batch x 4 vocab per block ----
  const int opo = tid >> 5, ln32 = tid & 31;
  const int opb = ((bid >> 4) << 2) + (opo >> 2);
  const int opv = ((bid & 15) << 2) + (opo & 3);
  const float boutv = bout[opv];

  // ---- reduce mapping: thread -> (row, col-quad) ----
  const int rm = tid >> 3;
  const int rng = (tid & 7) << 2;
  const int qcol = col0 + rng;
  float qb[4];
#pragma unroll
  for (int e = 0; e < 4; ++e)
    qb[e] = bxp[l * DD + qcol + e] + bhp[l * DD + qcol + e];
  const int qlen = slen[rm];

  // ---- staging lane decomposition (source pre-permuted; rule #21) ----
  const int lrow = lane >> 2;
  const int lelem = ((lane & 3) ^ ((lane >> 3) & 3)) << 3;
  const int fx = lr * 32 + ((q ^ ((lr >> 1) & 3)) << 3);

  // ---- gate scan flag indices (wave0, one group-member per lane) ----
  const int ia = (((l > 0 ? l - 1 : l) << 6) + lane) << 5;  // x producers
  const int ib = ((l << 6) + lane) << 5;                    // h producers
  const int ic = (((l < 3 ? l + 1 : l) << 6) + lane) << 5;  // slot consumers
  const int id = ((3 << 6) + lane) << 5;                    // group 3 (outproj)

  // LDS: stg (8 waves x 2 slots x 8KB = 128KB) UNION part[8][64][36] (72KB)
  __shared__ __align__(16) u16 stg[65536];
  float* part = (float*)stg;
  __shared__ int sids[64];
  __shared__ int ldsEp;
  __shared__ int ldsG3;

  u16* wslot = stg + (w << 13);
  volatile int* vep = (volatile int*)&ldsEp;
  volatile int* vg3 = (volatile int*)&ldsG3;

  if (tid == 0) { ldsEp = 0; ldsG3 = 0; }
  __syncthreads();

  int t_op = 0;  // next out-proj step to emit

  for (int t = 0; t < TT; ++t) {
    // ---------- dependency gate (wave0 scans, publishes to LDS) ----------
    if (w == 0) {
      int g3v;
      for (;;) {
        int a = __hip_atomic_load(&flags[ia], __ATOMIC_RELAXED,
                                  __HIP_MEMORY_SCOPE_AGENT);
        int b = __hip_atomic_load(&flags[ib], __ATOMIC_RELAXED,
                                  __HIP_MEMORY_SCOPE_AGENT);
        int c = __hip_atomic_load(&flags[ic], __ATOMIC_RELAXED,
                                  __HIP_MEMORY_SCOPE_AGENT);
        g3v = __hip_atomic_load(&flags[id], __ATOMIC_RELAXED,
                                __HIP_MEMORY_SCOPE_AGENT);
        int ok = (a >= t) & (b >= t) & (c >= t - 2);
        if (__all(ok)) break;
        __builtin_amdgcn_s_sleep(1);
      }
#pragma unroll
      for (int o = 32; o; o >>= 1) {
        int ov = __shfl_xor(g3v, o, 64);
        g3v = ov < g3v ? ov : g3v;
      }
      // amortized acquire: one L1/L2 inv per 4 own-steps covers ring reuse
      if ((t & 3) == 0 && lane == 0)
        (void)__hip_atomic_load(&flags[0], __ATOMIC_ACQUIRE,
                                __HIP_MEMORY_SCOPE_AGENT);
      __builtin_amdgcn_sched_barrier(0);
      if (lane == 0) { *vg3 = g3v; *vep = t + 1; }  // publish AFTER inv
    }
    while (*vep < t + 1) __builtin_amdgcn_s_sleep(1);
    const int g3cap = *vg3;  // outproj states < g3cap are ready (g3cap <= t)

    const u16* Hp = hb + (size_t)((t + 3) & 3) * HSZ;
    u16* Hc = hb + (size_t)(t & 3) * HSZ;

    // ---------- compute step t ----------
    if (l == 0) {
      if (tid < BB) sids[tid] = idsT[t * BB + tid];
      __syncthreads();
    }
    const int kw = (w << 8) + lelem;
    const u16* hb0 = Hp + (size_t)l * BB * DD + kw;
    const u16 *px0, *px1, *px2, *px3;
    if (l == 0) {
      px0 = embb + (size_t)sids[lrow] * DD + kw;
      px1 = embb + (size_t)sids[16 + lrow] * DD + kw;
      px2 = embb + (size_t)sids[32 + lrow] * DD + kw;
      px3 = embb + (size_t)sids[48 + lrow] * DD + kw;
    } else {
      const u16* xb0 = Hp + (size_t)(l - 1) * BB * DD + kw;
      px0 = xb0 + (size_t)lrow * DD;
      px1 = xb0 + (size_t)(16 + lrow) * DD;
      px2 = xb0 + (size_t)(32 + lrow) * DD;
      px3 = xb0 + (size_t)(48 + lrow) * DD;
    }
    const u16* ph0 = hb0 + (size_t)lrow * DD;
    const u16* ph1 = hb0 + (size_t)(16 + lrow) * DD;
    const u16* ph2 = hb0 + (size_t)(32 + lrow) * DD;
    const u16* ph3 = hb0 + (size_t)(48 + lrow) * DD;

#pragma unroll
    for (int c = 0; c < 2; ++c) {
      u16* d = wslot + (c << 12);
      GL(px0 + (c << 5), d);
      GL(px1 + (c << 5), d + 512);
      GL(px2 + (c << 5), d + 1024);
      GL(px3 + (c << 5), d + 1536);
      GL(ph0 + (c << 5), d + 2048);
      GL(ph1 + (c << 5), d + 2560);
      GL(ph2 + (c << 5), d + 3072);
      GL(ph3 + (c << 5), d + 3584);
    }

    f32x4 acc[2][4] = {{{0,0,0,0},{0,0,0,0},{0,0,0,0},{0,0,0,0}},
                       {{0,0,0,0},{0,0,0,0},{0,0,0,0},{0,0,0,0}}};
#pragma unroll
    for (int j = 0; j < 8; ++j) {
      if (j < 7) asm volatile("s_waitcnt vmcnt(8)" ::: "memory");
      else       asm volatile("s_waitcnt vmcnt(0)" ::: "memory");
      __builtin_amdgcn_sched_barrier(0);
      const u16* sb = wslot + ((j & 1) << 12);
      s16x8 ax0 = *(const s16x8*)(sb + fx);
      s16x8 ax1 = *(const s16x8*)(sb + 512 + fx);
      s16x8 ax2 = *(const s16x8*)(sb + 1024 + fx);
      s16x8 ax3 = *(const s16x8*)(sb + 1536 + fx);
      s16x8 ah0 = *(const s16x8*)(sb + 2048 + fx);
      s16x8 ah1 = *(const s16x8*)(sb + 2560 + fx);
      s16x8 ah2 = *(const s16x8*)(sb + 3072 + fx);
      s16x8 ah3 = *(const s16x8*)(sb + 3584 + fx);
      asm volatile("s_waitcnt lgkmcnt(0)" ::: "memory");
      __builtin_amdgcn_sched_barrier(0);
      if (j < 6) {
        u16* d = wslot + ((j & 1) << 12);
        const int co = (j + 2) << 5;
        GL(px0 + co, d);
        GL(px1 + co, d + 512);
        GL(px2 + co, d + 1024);
        GL(px3 + co, d + 1536);
        GL(ph0 + co, d + 2048);
        GL(ph1 + co, d + 2560);
        GL(ph2 + co, d + 3072);
        GL(ph3 + co, d + 3584);
      }
#pragma unroll
      for (int c = 0; c < 2; ++c) {
        acc[c][0] = MFMA(ax0, wx[c][j], acc[c][0]);
        acc[c][0] = MFMA(ah0, wh[c][j], acc[c][0]);
        acc[c][1] = MFMA(ax1, wx[c][j], acc[c][1]);
        acc[c][1] = MFMA(ah1, wh[c][j], acc[c][1]);
        acc[c][2] = MFMA(ax2, wx[c][j], acc[c][2]);
        acc[c][2] = MFMA(ah2, wh[c][j], acc[c][2]);
        acc[c][3] = MFMA(ax3, wx[c][j], acc[c][3]);
        acc[c][3] = MFMA(ah3, wh[c][j], acc[c][3]);
      }
    }

    __syncthreads();  // all waves done reading stg; part may overwrite
#pragma unroll
    for (int c = 0; c < 2; ++c)
#pragma unroll
      for (int mt = 0; mt < 4; ++mt)
#pragma unroll
        for (int i = 0; i < 4; ++i)
          part[((w << 6) + (mt << 4) + (q << 2) + i) * 36 + (c << 4) + lr] =
              acc[c][mt][i];
    __syncthreads();

    // 8-way K-combine + bias + tanh + mask + packed agent write-through store
    {
      f32x4 sum = {0, 0, 0, 0};
#pragma unroll
      for (int k2 = 0; k2 < 8; ++k2)
        sum += *(const f32x4*)&part[((k2 << 6) + rm) * 36 + rng];
      float h0 = tanhf(sum[0] + qb[0]);
      float h1 = tanhf(sum[1] + qb[1]);
      float h2 = tanhf(sum[2] + qb[2]);
      float h3 = tanhf(sum[3] + qb[3]);
      size_t idx = ((size_t)l * BB + rm) * DD + qcol;
      u64 pk = (u64)f2b(h0) | ((u64)f2b(h1) << 16) |
               ((u64)f2b(h2) << 32) | ((u64)f2b(h3) << 48);
      u64 val = (t < qlen) ? pk : *(const u64*)(Hp + idx);
      __hip_atomic_store((u64*)(Hc + idx), val, __ATOMIC_RELAXED,
                         __HIP_MEMORY_SCOPE_AGENT);
      if (l == 3)  // also append h3 slice to 16-deep history ring
        __hip_atomic_store((u64*)(hist + (size_t)(t & 15) * H3SZ +
                                  (size_t)rm * DD + qcol),
                           val, __ATOMIC_RELAXED, __HIP_MEMORY_SCOPE_AGENT);
    }
    asm volatile("s_waitcnt vmcnt(0)" ::: "memory");
    __syncthreads();  // all waves' stores drained

    if (tid == 0)
      __hip_atomic_store(&flags[bid << 5], t + 1, __ATOMIC_RELAXED,
                         __HIP_MEMORY_SCOPE_AGENT);

    // ---------- lazy out-proj drain (overlaps peers' progress) ----------
    while (t_op < g3cap) {
      const u16* h3p = hist + (size_t)(t_op & 15) * H3SZ;
      const u16* hp = h3p + (size_t)opb * DD + (ln32 << 6);
      const u16* wp = WoT + (size_t)opv * DD + (ln32 << 6);
      float sacc = 0.f;
#pragma unroll
      for (int j = 0; j < 64; j += 8) {
        s16x8 hv8 = *(const s16x8*)(hp + j);
        s16x8 wv8 = *(const s16x8*)(wp + j);
#pragma unroll
        for (int e = 0; e < 8; ++e)
          sacc = fmaf(b2f((u16)hv8[e]), b2f((u16)wv8[e]), sacc);
      }
#pragma unroll
      for (int d = 16; d > 0; d >>= 1) sacc += __shfl_xor(sacc, d, 64);
      if (ln32 == 0)
        out[((size_t)opb * TT + t_op) * VV + opv] = sacc + boutv;
      ++t_op;
    }
  }

  // ---------- final drain: finish out-proj through TT-1 ----------
  while (t_op < TT) {
    if (w == 0) {
      int g3v = __hip_atomic_load(&flags[id], __ATOMIC_RELAXED,
                                  __HIP_MEMORY_SCOPE_AGENT);
#pragma unroll
      for (int o = 32; o; o >>= 1) {
        int ov = __shfl_xor(g3v, o, 64);
        g3v = ov < g3v ? ov : g3v;
      }
      if (lane == 0) {
        (void)__hip_atomic_load(&flags[0], __ATOMIC_ACQUIRE,
                                __HIP_MEMORY_SCOPE_AGENT);
        *vg3 = g3v;
      }
    }
    __syncthreads();
    const int cap = *vg3 < TT ? *vg3 : TT;
    while (t_op < cap) {
      const u16* h3p = hist + (size_t)(t_op & 15) * H3SZ;
      const u16* hp = h3p + (size_t)opb * DD + (ln32 << 6);
      const u16* wp = WoT + (size_t)opv * DD + (ln32 << 6);
      float sacc = 0.f;
#pragma unroll
      for (int j = 0; j < 64; j += 8) {
        s16x8 hv8 = *(const s16x8*)(hp + j);
        s16x8 wv8 = *(const s16x8*)(wp + j);
#pragma unroll
        for (int e = 0; e < 8; ++e)
          sacc = fmaf(b2f((u16)hv8[e]), b2f((u16)wv8[e]), sacc);
      }
#pragma unroll
      for (int d = 16; d > 0; d >>= 1) sacc += __shfl_xor(sacc, d, 64);
      if (ln32 == 0)
        out[((size_t)opb * TT + t_op) * VV + opv] = sacc + boutv;
      ++t_op;
    }
    if (t_op < TT) __builtin_amdgcn_s_sleep(4);
    __syncthreads();
  }
}

extern "C" void kernel_launch(void* const* d_in, const int* in_sizes, int n_in,
                              void* d_out, int out_size, void* d_ws, size_t ws_size,
                              hipStream_t stream) {
  const int* ids = (const int*)d_in[0];
  const int* slen = (const int*)d_in[1];
  const float* emb = (const float*)d_in[2];
  const float* Wx = (const float*)d_in[3];
  const float* bx = (const float*)d_in[4];
  const float* Wh = (const float*)d_in[5];
  const float* bh = (const float*)d_in[6];
  const float* Wout = (const float*)d_in[7];
  const float* bout = (const float*)d_in[8];
  float* out = (float*)d_out;

  char* ws = (char*)d_ws;
  const size_t oW = (size_t)LL * DD * DD * 2;
  const size_t oWoT = (size_t)VV * DD * 2;
  const size_t oEmb = (size_t)VV * DD * 2;
  const size_t oHb = (size_t)LL * BB * DD * 2;
  const size_t oH3 = (size_t)BB * DD * 2;
  u16* Wxb = (u16*)ws;
  u16* Whb = (u16*)(ws + oW);
  u16* WoT = (u16*)(ws + 2 * oW);
  u16* embb = (u16*)(ws + 2 * oW + oWoT);
  u16* hb = (u16*)(ws + 2 * oW + oWoT + oEmb);            // 4-ring state
  int* flags = (int*)(ws + 2 * oW + oWoT + oEmb + 4 * oHb);
  int* idsT = (int*)(ws + 2 * oW + oWoT + oEmb + 4 * oHb + 32768);
  u16* hist = (u16*)(ws + 2 * oW + oWoT + oEmb + 4 * oHb + 32768 + 131072);

  hipMemsetAsync(ws + 2 * oW + oWoT + oEmb, 0, 4 * oHb + 32768, stream);

  const size_t n4 = (size_t)LL * DD * DD / 4;
  convert_w<<<dim3(4096), dim3(256), 0, stream>>>(Wx, Wxb, n4);
  convert_w<<<dim3(4096), dim3(256), 0, stream>>>(Wh, Whb, n4);
  convert_w<<<dim3(128), dim3(256), 0, stream>>>(emb, embb, (size_t)VV * DD / 4);
  convert_woT<<<dim3(512), dim3(256), 0, stream>>>(Wout, WoT);
  transpose_ids<<<dim3(128), dim3(256), 0, stream>>>(ids, idsT);

  void* kp[13];
  kp[0] = (void*)&idsT; kp[1] = (void*)&slen;
  kp[2] = (void*)&bx;   kp[3] = (void*)&bh;   kp[4] = (void*)&embb;
  kp[5] = (void*)&Wxb;  kp[6] = (void*)&Whb;  kp[7] = (void*)&WoT;
  kp[8] = (void*)&bout; kp[9] = (void*)&hb;   kp[10] = (void*)&hist;
  kp[11] = (void*)&out; kp[12] = (void*)&flags;
  hipLaunchCooperativeKernel((const void*)persist, dim3(256), dim3(512), kp, 0, stream);
}

// Round 15
// 7627.348 us; speedup vs baseline: 1.0807x; 1.0275x over previous
//
#include <hip/hip_runtime.h>
#include <hip/hip_bf16.h>

#define TT 512
#define BB 64
#define DD 2048
#define LL 4
#define VV 64

typedef unsigned short u16;
typedef unsigned int u32;
typedef unsigned long long u64;
typedef __attribute__((ext_vector_type(8))) short s16x8;
typedef __attribute__((ext_vector_type(4))) float f32x4;

#define MFMA(a, b, c) __builtin_amdgcn_mfma_f32_16x16x32_bf16((a), (b), (c), 0, 0, 0)

#define GL(gp, lp)                                                        \
  __builtin_amdgcn_global_load_lds(                                       \
      (const __attribute__((address_space(1))) void*)(gp),                \
      (__attribute__((address_space(3))) void*)(lp), 16, 0, 0)

__device__ inline u16 f2b(float f) {
  u32 u = __builtin_bit_cast(u32, f);
  u32 r = (u + 0x7fffu + ((u >> 16) & 1u)) >> 16;
  return (u16)r;
}
__device__ inline float b2f(u16 b) {
  u32 u = ((u32)b) << 16;
  return __builtin_bit_cast(float, u);
}

__global__ __launch_bounds__(256) void convert_w(const float* __restrict__ src,
                                                 u16* __restrict__ dst, size_t n4) {
  size_t i = (size_t)blockIdx.x * 256 + threadIdx.x;
  size_t stride = (size_t)gridDim.x * 256;
  for (size_t j = i; j < n4; j += stride) {
    float4 f = ((const float4*)src)[j];
    ushort4 o;
    o.x = f2b(f.x); o.y = f2b(f.y); o.z = f2b(f.z); o.w = f2b(f.w);
    ((ushort4*)dst)[j] = o;
  }
}

__global__ __launch_bounds__(256) void convert_woT(const float* __restrict__ Wout,
                                                   u16* __restrict__ WoT) {
  int g = blockIdx.x * 256 + threadIdx.x;
  int v = g >> 11, k = g & 2047;
  WoT[(size_t)v * DD + k] = f2b(Wout[(size_t)k * VV + v]);
}

__global__ __launch_bounds__(256) void transpose_ids(const int* __restrict__ ids,
                                                     int* __restrict__ idsT) {
  int g = blockIdx.x * 256 + threadIdx.x;
  int b = g >> 9, t = g & 511;
  idsT[t * BB + b] = ids[b * TT + t];
}

// Persistent: 256 blocks x 512 threads, 1 block/CU. Block -> (layer, 32 cols).
// 8 waves split K; wave-private LDS dbuf staging via global_load_lds, counted
// vmcnt. Weights pinned in regs. State: 4-ring, AGENT write-through stores,
// acquire-inv every 4 steps. Barrier: flag store + all-block scan with
// out-proj overlapped inside the wait (R12 structure, session-best 7.63ms).
// THIS ROUND'S DELTA: spin loops are HOT (no s_sleep) to deny the DPM
// governor its idle signal and hold the shader clock up during waits.
__global__ __launch_bounds__(512, 2)
void persist(const int* __restrict__ idsT, const int* __restrict__ slen,
             const float* __restrict__ bxp, const float* __restrict__ bhp,
             const u16* __restrict__ embb,
             const u16* __restrict__ Wxb, const u16* __restrict__ Whb,
             const u16* __restrict__ WoT, const float* __restrict__ bout,
             u16* hb, float* __restrict__ out, int* flags) {
  const int tid = threadIdx.x, bid = blockIdx.x;
  const int l = bid >> 6;
  const int col0 = (bid & 63) << 5;
  const int w = tid >> 6, lane = tid & 63;
  const int lr = lane & 15, q = lane >> 4;
  const size_t HSZ = (size_t)LL * BB * DD;

  // ---- weight frags: [ctile][chunk], k = w*256 + j*32 + q*8 ----
  s16x8 wx[2][8], wh[2][8];
#pragma unroll
  for (int c = 0; c < 2; ++c) {
    const int ncol = col0 + (c << 4) + lr;
    const u16* p0 = Wxb + ((size_t)l * DD + ncol) * DD + (w << 8) + (q << 3);
    const u16* p1 = Whb + ((size_t)l * DD + ncol) * DD + (w << 8) + (q << 3);
#pragma unroll
    for (int j = 0; j < 8; ++j) {
      wx[c][j] = *(const s16x8*)(p0 + (j << 5));
      wh[c][j] = *(const s16x8*)(p1 + (j << 5));
    }
  }
#pragma unroll
  for (int c = 0; c < 2; ++c)
#pragma unroll
    for (int j = 0; j < 8; ++j) {
      asm("" : "+v"(wx[c][j]));
      asm("" : "+v"(wh[c][j]));
    }

  // ---- out-proj: 4 batch x 4 vocab per block ----
  const int opo = tid >> 5, ln32 = tid & 31;
  const int opb = ((bid >> 4) << 2) + (opo >> 2);
  const int opv = ((bid & 15) << 2) + (opo & 3);
  const float boutv = bout[opv];

  // ---- reduce mapping: thread -> (row, col-quad) ----
  const int rm = tid >> 3;
  const int rng = (tid & 7) << 2;
  const int qcol = col0 + rng;
  float qb[4];
#pragma unroll
  for (int e = 0; e < 4; ++e)
    qb[e] = bxp[l * DD + qcol + e] + bhp[l * DD + qcol + e];
  const int qlen = slen[rm];

  // ---- staging lane decomposition (source pre-permuted; rule #21) ----
  const int lrow = lane >> 2;
  const int lelem = ((lane & 3) ^ ((lane >> 3) & 3)) << 3;
  const int fx = lr * 32 + ((q ^ ((lr >> 1) & 3)) << 3);

  const int fidx = ((w << 5) + (lane & 31)) << 5;  // barrier scan flag

  // LDS: stg (8 waves x 2 slots x 8KB = 128KB) UNION part[8][64][36] (72KB)
  __shared__ __align__(16) u16 stg[65536];
  float* part = (float*)stg;
  __shared__ int sids[64];
  __shared__ int wok[8];
  __shared__ int alldone;

  u16* wslot = stg + (w << 13);

  for (int t = 0; t <= TT; ++t) {
    const u16* Hp = hb + (size_t)((t + 3) & 3) * HSZ;
    u16* Hc = hb + (size_t)(t & 3) * HSZ;

    if (t < TT) {
      if (l == 0) {
        if (tid < BB) sids[tid] = idsT[t * BB + tid];
        __syncthreads();
      }
      const int kw = (w << 8) + lelem;
      const u16* hb0 = Hp + (size_t)l * BB * DD + kw;
      const u16 *px0, *px1, *px2, *px3;
      if (l == 0) {
        px0 = embb + (size_t)sids[lrow] * DD + kw;
        px1 = embb + (size_t)sids[16 + lrow] * DD + kw;
        px2 = embb + (size_t)sids[32 + lrow] * DD + kw;
        px3 = embb + (size_t)sids[48 + lrow] * DD + kw;
      } else {
        const u16* xb0 = Hp + (size_t)(l - 1) * BB * DD + kw;
        px0 = xb0 + (size_t)lrow * DD;
        px1 = xb0 + (size_t)(16 + lrow) * DD;
        px2 = xb0 + (size_t)(32 + lrow) * DD;
        px3 = xb0 + (size_t)(48 + lrow) * DD;
      }
      const u16* ph0 = hb0 + (size_t)lrow * DD;
      const u16* ph1 = hb0 + (size_t)(16 + lrow) * DD;
      const u16* ph2 = hb0 + (size_t)(32 + lrow) * DD;
      const u16* ph3 = hb0 + (size_t)(48 + lrow) * DD;

      // prologue: stage chunks 0,1 (8 GLs each)
#pragma unroll
      for (int c = 0; c < 2; ++c) {
        u16* d = wslot + (c << 12);
        GL(px0 + (c << 5), d);
        GL(px1 + (c << 5), d + 512);
        GL(px2 + (c << 5), d + 1024);
        GL(px3 + (c << 5), d + 1536);
        GL(ph0 + (c << 5), d + 2048);
        GL(ph1 + (c << 5), d + 2560);
        GL(ph2 + (c << 5), d + 3072);
        GL(ph3 + (c << 5), d + 3584);
      }

      f32x4 acc[2][4] = {{{0,0,0,0},{0,0,0,0},{0,0,0,0},{0,0,0,0}},
                         {{0,0,0,0},{0,0,0,0},{0,0,0,0},{0,0,0,0}}};
#pragma unroll
      for (int j = 0; j < 8; ++j) {
        if (j < 7) asm volatile("s_waitcnt vmcnt(8)" ::: "memory");
        else       asm volatile("s_waitcnt vmcnt(0)" ::: "memory");
        __builtin_amdgcn_sched_barrier(0);
        const u16* sb = wslot + ((j & 1) << 12);
        s16x8 ax0 = *(const s16x8*)(sb + fx);
        s16x8 ax1 = *(const s16x8*)(sb + 512 + fx);
        s16x8 ax2 = *(const s16x8*)(sb + 1024 + fx);
        s16x8 ax3 = *(const s16x8*)(sb + 1536 + fx);
        s16x8 ah0 = *(const s16x8*)(sb + 2048 + fx);
        s16x8 ah1 = *(const s16x8*)(sb + 2560 + fx);
        s16x8 ah2 = *(const s16x8*)(sb + 3072 + fx);
        s16x8 ah3 = *(const s16x8*)(sb + 3584 + fx);
        asm volatile("s_waitcnt lgkmcnt(0)" ::: "memory");
        __builtin_amdgcn_sched_barrier(0);
        if (j < 6) {
          u16* d = wslot + ((j & 1) << 12);
          const int co = (j + 2) << 5;
          GL(px0 + co, d);
          GL(px1 + co, d + 512);
          GL(px2 + co, d + 1024);
          GL(px3 + co, d + 1536);
          GL(ph0 + co, d + 2048);
          GL(ph1 + co, d + 2560);
          GL(ph2 + co, d + 3072);
          GL(ph3 + co, d + 3584);
        }
#pragma unroll
        for (int c = 0; c < 2; ++c) {
          acc[c][0] = MFMA(ax0, wx[c][j], acc[c][0]);
          acc[c][0] = MFMA(ah0, wh[c][j], acc[c][0]);
          acc[c][1] = MFMA(ax1, wx[c][j], acc[c][1]);
          acc[c][1] = MFMA(ah1, wh[c][j], acc[c][1]);
          acc[c][2] = MFMA(ax2, wx[c][j], acc[c][2]);
          acc[c][2] = MFMA(ah2, wh[c][j], acc[c][2]);
          acc[c][3] = MFMA(ax3, wx[c][j], acc[c][3]);
          acc[c][3] = MFMA(ah3, wh[c][j], acc[c][3]);
        }
      }

      __syncthreads();  // all waves done reading stg; part may overwrite
#pragma unroll
      for (int c = 0; c < 2; ++c)
#pragma unroll
        for (int mt = 0; mt < 4; ++mt)
#pragma unroll
          for (int i = 0; i < 4; ++i)
            part[((w << 6) + (mt << 4) + (q << 2) + i) * 36 + (c << 4) + lr] =
                acc[c][mt][i];
      __syncthreads();

      // 8-way K-combine + bias + tanh + mask + packed agent write-through store
      {
        f32x4 sum = {0, 0, 0, 0};
#pragma unroll
        for (int k2 = 0; k2 < 8; ++k2)
          sum += *(const f32x4*)&part[((k2 << 6) + rm) * 36 + rng];
        float h0 = tanhf(sum[0] + qb[0]);
        float h1 = tanhf(sum[1] + qb[1]);
        float h2 = tanhf(sum[2] + qb[2]);
        float h3 = tanhf(sum[3] + qb[3]);
        size_t idx = ((size_t)l * BB + rm) * DD + qcol;
        u64 pk = (u64)f2b(h0) | ((u64)f2b(h1) << 16) |
                 ((u64)f2b(h2) << 32) | ((u64)f2b(h3) << 48);
        u64 val = (t < qlen) ? pk : *(const u64*)(Hp + idx);
        __hip_atomic_store((u64*)(Hc + idx), val, __ATOMIC_RELAXED,
                           __HIP_MEMORY_SCOPE_AGENT);
      }
      asm volatile("s_waitcnt vmcnt(0)" ::: "memory");
    }
    __syncthreads();

    const int ep = t + 1;
    if (t < TT && tid == 0)
      __hip_atomic_store(&flags[bid << 5], ep, __ATOMIC_RELAXED,
                         __HIP_MEMORY_SCOPE_AGENT);

    // out-proj for step t-1 (Hp), overlapped with other blocks' arrivals
    if (t > 0) {
      const u16* h3p = Hp + (size_t)3 * BB * DD;
      const u16* hp = h3p + (size_t)opb * DD + (ln32 << 6);
      const u16* wp = WoT + (size_t)opv * DD + (ln32 << 6);
      float sacc = 0.f;
#pragma unroll
      for (int j = 0; j < 64; j += 8) {
        s16x8 hv8 = *(const s16x8*)(hp + j);
        s16x8 wv8 = *(const s16x8*)(wp + j);
#pragma unroll
        for (int e = 0; e < 8; ++e)
          sacc = fmaf(b2f((u16)hv8[e]), b2f((u16)wv8[e]), sacc);
      }
#pragma unroll
      for (int d = 16; d > 0; d >>= 1) sacc += __shfl_xor(sacc, d, 64);
      if (ln32 == 0)
        out[((size_t)opb * TT + (t - 1)) * VV + opv] = sacc + boutv;
    }

    if (t < TT) {
      for (;;) {   // HOT spin: no s_sleep (keep clocks up)
        int f = ep;
        if (lane < 32)
          f = __hip_atomic_load(&flags[fidx], __ATOMIC_RELAXED,
                                __HIP_MEMORY_SCOPE_AGENT);
        int ok = __all(f - ep >= 0);
        if (lane == 0) wok[w] = ok;
        __syncthreads();
        if (tid == 0)
          alldone = wok[0] & wok[1] & wok[2] & wok[3] &
                    wok[4] & wok[5] & wok[6] & wok[7];
        __syncthreads();
        if (alldone) break;
      }
      if ((ep & 3) == 0 && tid == 0)
        __hip_atomic_load(&flags[0], __ATOMIC_ACQUIRE, __HIP_MEMORY_SCOPE_AGENT);
      __syncthreads();
    }
  }
}

extern "C" void kernel_launch(void* const* d_in, const int* in_sizes, int n_in,
                              void* d_out, int out_size, void* d_ws, size_t ws_size,
                              hipStream_t stream) {
  const int* ids = (const int*)d_in[0];
  const int* slen = (const int*)d_in[1];
  const float* emb = (const float*)d_in[2];
  const float* Wx = (const float*)d_in[3];
  const float* bx = (const float*)d_in[4];
  const float* Wh = (const float*)d_in[5];
  const float* bh = (const float*)d_in[6];
  const float* Wout = (const float*)d_in[7];
  const float* bout = (const float*)d_in[8];
  float* out = (float*)d_out;

  char* ws = (char*)d_ws;
  const size_t oW = (size_t)LL * DD * DD * 2;
  const size_t oWoT = (size_t)VV * DD * 2;
  const size_t oEmb = (size_t)VV * DD * 2;
  const size_t oHb = (size_t)LL * BB * DD * 2;
  u16* Wxb = (u16*)ws;
  u16* Whb = (u16*)(ws + oW);
  u16* WoT = (u16*)(ws + 2 * oW);
  u16* embb = (u16*)(ws + 2 * oW + oWoT);
  u16* hb = (u16*)(ws + 2 * oW + oWoT + oEmb);          // 4-ring state
  int* flags = (int*)(ws + 2 * oW + oWoT + oEmb + 4 * oHb);
  int* idsT = (int*)(ws + 2 * oW + oWoT + oEmb + 4 * oHb + 32768);

  hipMemsetAsync(ws + 2 * oW + oWoT + oEmb, 0, 4 * oHb + 32768, stream);

  const size_t n4 = (size_t)LL * DD * DD / 4;
  convert_w<<<dim3(4096), dim3(256), 0, stream>>>(Wx, Wxb, n4);
  convert_w<<<dim3(4096), dim3(256), 0, stream>>>(Wh, Whb, n4);
  convert_w<<<dim3(128), dim3(256), 0, stream>>>(emb, embb, (size_t)VV * DD / 4);
  convert_woT<<<dim3(512), dim3(256), 0, stream>>>(Wout, WoT);
  transpose_ids<<<dim3(128), dim3(256), 0, stream>>>(ids, idsT);

  void* kp[12];
  kp[0] = (void*)&idsT; kp[1] = (void*)&slen;
  kp[2] = (void*)&bx;   kp[3] = (void*)&bh;   kp[4] = (void*)&embb;
  kp[5] = (void*)&Wxb;  kp[6] = (void*)&Whb;  kp[7] = (void*)&WoT;
  kp[8] = (void*)&bout; kp[9] = (void*)&hb;   kp[10] = (void*)&out;
  kp[11] = (void*)&flags;
  hipLaunchCooperativeKernel((const void*)persist, dim3(256), dim3(512), kp, 0, stream);
}

// Round 16
// 5684.595 us; speedup vs baseline: 1.4500x; 1.3418x over previous
//
#include <hip/hip_runtime.h>
#include <hip/hip_bf16.h>

#define TT 512
#define BB 64
#define DD 2048
#define LL 4
#define VV 64

typedef unsigned short u16;
typedef unsigned int u32;
typedef unsigned long long u64;
typedef __attribute__((ext_vector_type(8))) short s16x8;
typedef __attribute__((ext_vector_type(4))) float f32x4;

#define MFMA(a, b, c) __builtin_amdgcn_mfma_f32_16x16x32_bf16((a), (b), (c), 0, 0, 0)

#define GL(gp, lp)                                                        \
  __builtin_amdgcn_global_load_lds(                                       \
      (const __attribute__((address_space(1))) void*)(gp),                \
      (__attribute__((address_space(3))) void*)(lp), 16, 0, 0)

__device__ inline u16 f2b(float f) {
  u32 u = __builtin_bit_cast(u32, f);
  u32 r = (u + 0x7fffu + ((u >> 16) & 1u)) >> 16;
  return (u16)r;
}
__device__ inline float b2f(u16 b) {
  u32 u = ((u32)b) << 16;
  return __builtin_bit_cast(float, u);
}

__global__ __launch_bounds__(256) void convert_w(const float* __restrict__ src,
                                                 u16* __restrict__ dst, size_t n4) {
  size_t i = (size_t)blockIdx.x * 256 + threadIdx.x;
  size_t stride = (size_t)gridDim.x * 256;
  for (size_t j = i; j < n4; j += stride) {
    float4 f = ((const float4*)src)[j];
    ushort4 o;
    o.x = f2b(f.x); o.y = f2b(f.y); o.z = f2b(f.z); o.w = f2b(f.w);
    ((ushort4*)dst)[j] = o;
  }
}

__global__ __launch_bounds__(256) void convert_woT(const float* __restrict__ Wout,
                                                   u16* __restrict__ WoT) {
  int g = blockIdx.x * 256 + threadIdx.x;
  int v = g >> 11, k = g & 2047;
  WoT[(size_t)v * DD + k] = f2b(Wout[(size_t)k * VV + v]);
}

// stable rank-sort of 64 rows by descending slen; nact[t] = #{slen+4 > t}
__global__ __launch_bounds__(64) void prep64(const int* __restrict__ slen,
                                             int* __restrict__ perm,
                                             int* __restrict__ slenP,
                                             int* __restrict__ nact) {
  __shared__ int sperm[64];
  const int b = threadIdx.x;
  const int s = slen[b];
  int r = 0;
  for (int j = 0; j < 64; ++j) {
    int sj = slen[j];
    r += (sj > s) || ((sj == s) && (j < b));
  }
  sperm[r] = b;
  __syncthreads();
  perm[b] = sperm[b];
  slenP[b] = slen[sperm[b]];
  for (int t = b; t < TT; t += 64) {
    int c = 0;
    for (int j = 0; j < 64; ++j) c += (slen[j] + 4 > t) ? 1 : 0;
    nact[t] = c;
  }
}

// idsT[t][j] = ids[perm[j]][t]
__global__ __launch_bounds__(256) void transpose_ids_p(const int* __restrict__ ids,
                                                       const int* __restrict__ perm,
                                                       int* __restrict__ idsT) {
  int g = blockIdx.x * 256 + threadIdx.x;  // 32768
  int t = g >> 6, j = g & 63;
  idsT[t * BB + j] = ids[perm[j] * TT + t];
}

// Persistent: 256 blocks x 512 threads, 1 block/CU. Block -> (layer, 32 cols).
// R12/R15 structure (session best) + ACTIVITY SCALING: batch rows permuted by
// descending slen; at step t only row-groups < ng = ceil(nact(t)/16) are
// staged/computed/stored (nact counts slen+4 > t; the +4 pad guarantees >=4
// carry-writes after freeze, so skipped rows are frozen in ALL 4 ring
// buffers). Sync, staging pipeline, numerics all unchanged.
__global__ __launch_bounds__(512, 2)
void persist(const int* __restrict__ idsT, const int* __restrict__ slenP,
             const float* __restrict__ bxp, const float* __restrict__ bhp,
             const u16* __restrict__ embb,
             const u16* __restrict__ Wxb, const u16* __restrict__ Whb,
             const u16* __restrict__ WoT, const float* __restrict__ bout,
             u16* hb, float* __restrict__ out, int* flags,
             const int* __restrict__ perm, const int* __restrict__ nact) {
  const int tid = threadIdx.x, bid = blockIdx.x;
  const int l = bid >> 6;
  const int col0 = (bid & 63) << 5;
  const int w = tid >> 6, lane = tid & 63;
  const int lr = lane & 15, q = lane >> 4;
  const size_t HSZ = (size_t)LL * BB * DD;

  // ---- weight frags: [ctile][chunk], k = w*256 + j*32 + q*8 ----
  s16x8 wx[2][8], wh[2][8];
#pragma unroll
  for (int c = 0; c < 2; ++c) {
    const int ncol = col0 + (c << 4) + lr;
    const u16* p0 = Wxb + ((size_t)l * DD + ncol) * DD + (w << 8) + (q << 3);
    const u16* p1 = Whb + ((size_t)l * DD + ncol) * DD + (w << 8) + (q << 3);
#pragma unroll
    for (int j = 0; j < 8; ++j) {
      wx[c][j] = *(const s16x8*)(p0 + (j << 5));
      wh[c][j] = *(const s16x8*)(p1 + (j << 5));
    }
  }
#pragma unroll
  for (int c = 0; c < 2; ++c)
#pragma unroll
    for (int j = 0; j < 8; ++j) {
      asm("" : "+v"(wx[c][j]));
      asm("" : "+v"(wh[c][j]));
    }

  // ---- out-proj: 4 batch x 4 vocab per block (perm'd output row) ----
  const int opo = tid >> 5, ln32 = tid & 31;
  const int opb = ((bid >> 4) << 2) + (opo >> 2);
  const int opv = ((bid & 15) << 2) + (opo & 3);
  const int pbr = perm[opb];
  const float boutv = bout[opv];

  // ---- reduce mapping: thread -> (row, col-quad) ----
  const int rm = tid >> 3;
  const int rng = (tid & 7) << 2;
  const int qcol = col0 + rng;
  float qb[4];
#pragma unroll
  for (int e = 0; e < 4; ++e)
    qb[e] = bxp[l * DD + qcol + e] + bhp[l * DD + qcol + e];
  const int qlen = slenP[rm];

  // ---- staging lane decomposition (source pre-permuted; rule #21) ----
  const int lrow = lane >> 2;
  const int lelem = ((lane & 3) ^ ((lane >> 3) & 3)) << 3;
  const int fx = lr * 32 + ((q ^ ((lr >> 1) & 3)) << 3);

  const int fidx = ((w << 5) + (lane & 31)) << 5;  // barrier scan flag

  // LDS: stg (8 waves x 2 slots x 8KB = 128KB) UNION part[8][64][36] (72KB)
  __shared__ __align__(16) u16 stg[65536];
  float* part = (float*)stg;
  __shared__ int sids[64];
  __shared__ int wok[8];
  __shared__ int alldone;

  u16* wslot = stg + (w << 13);

  for (int t = 0; t <= TT; ++t) {
    const u16* Hp = hb + (size_t)((t + 3) & 3) * HSZ;
    u16* Hc = hb + (size_t)(t & 3) * HSZ;

    if (t < TT) {
      const int ng = (nact[t] + 15) >> 4;  // active row-groups (0..4), uniform

      if (l == 0) {
        if (tid < BB) sids[tid] = idsT[t * BB + tid];
        __syncthreads();
      }
      const int kw = (w << 8) + lelem;
      const u16* hb0 = Hp + (size_t)l * BB * DD + kw;
      const u16* px[4];
      const u16* ph[4];
      if (l == 0) {
        px[0] = embb + (size_t)sids[lrow] * DD + kw;
        px[1] = embb + (size_t)sids[16 + lrow] * DD + kw;
        px[2] = embb + (size_t)sids[32 + lrow] * DD + kw;
        px[3] = embb + (size_t)sids[48 + lrow] * DD + kw;
      } else {
        const u16* xb0 = Hp + (size_t)(l - 1) * BB * DD + kw;
        px[0] = xb0 + (size_t)lrow * DD;
        px[1] = xb0 + (size_t)(16 + lrow) * DD;
        px[2] = xb0 + (size_t)(32 + lrow) * DD;
        px[3] = xb0 + (size_t)(48 + lrow) * DD;
      }
      ph[0] = hb0 + (size_t)lrow * DD;
      ph[1] = hb0 + (size_t)(16 + lrow) * DD;
      ph[2] = hb0 + (size_t)(32 + lrow) * DD;
      ph[3] = hb0 + (size_t)(48 + lrow) * DD;

      // prologue: stage chunks 0,1 (2*ng GLs each)
#pragma unroll
      for (int c = 0; c < 2; ++c) {
        u16* d = wslot + (c << 12);
#pragma unroll
        for (int r = 0; r < 4; ++r)
          if (r < ng) {
            GL(px[r] + (c << 5), d + (r << 9));
            GL(ph[r] + (c << 5), d + 2048 + (r << 9));
          }
      }

      f32x4 acc[2][4] = {{{0,0,0,0},{0,0,0,0},{0,0,0,0},{0,0,0,0}},
                         {{0,0,0,0},{0,0,0,0},{0,0,0,0},{0,0,0,0}}};
#pragma unroll
      for (int j = 0; j < 8; ++j) {
        if (j < 7) {  // one chunk (2*ng loads) may remain outstanding
          if (ng == 4)      asm volatile("s_waitcnt vmcnt(8)" ::: "memory");
          else if (ng == 3) asm volatile("s_waitcnt vmcnt(6)" ::: "memory");
          else if (ng == 2) asm volatile("s_waitcnt vmcnt(4)" ::: "memory");
          else              asm volatile("s_waitcnt vmcnt(2)" ::: "memory");
        } else {
          asm volatile("s_waitcnt vmcnt(0)" ::: "memory");
        }
        __builtin_amdgcn_sched_barrier(0);
        const u16* sb = wslot + ((j & 1) << 12);
        s16x8 ax[4], ah[4];
#pragma unroll
        for (int r = 0; r < 4; ++r)
          if (r < ng) {
            ax[r] = *(const s16x8*)(sb + (r << 9) + fx);
            ah[r] = *(const s16x8*)(sb + 2048 + (r << 9) + fx);
          }
        asm volatile("s_waitcnt lgkmcnt(0)" ::: "memory");
        __builtin_amdgcn_sched_barrier(0);
        if (j < 6) {  // refill same slot with chunk j+2 (reads done)
          u16* d = wslot + ((j & 1) << 12);
          const int co = (j + 2) << 5;
#pragma unroll
          for (int r = 0; r < 4; ++r)
            if (r < ng) {
              GL(px[r] + co, d + (r << 9));
              GL(ph[r] + co, d + 2048 + (r << 9));
            }
        }
#pragma unroll
        for (int c = 0; c < 2; ++c)
#pragma unroll
          for (int r = 0; r < 4; ++r)
            if (r < ng) {
              acc[c][r] = MFMA(ax[r], wx[c][j], acc[c][r]);
              acc[c][r] = MFMA(ah[r], wh[c][j], acc[c][r]);
            }
      }

      __syncthreads();  // all waves done reading stg; part may overwrite
#pragma unroll
      for (int c = 0; c < 2; ++c)
#pragma unroll
        for (int mt = 0; mt < 4; ++mt)
          if (mt < ng)
#pragma unroll
            for (int i = 0; i < 4; ++i)
              part[((w << 6) + (mt << 4) + (q << 2) + i) * 36 + (c << 4) + lr] =
                  acc[c][mt][i];
      __syncthreads();

      // 8-way K-combine + bias + tanh + mask + packed agent write-through store
      if (rm < (ng << 4)) {
        f32x4 sum = {0, 0, 0, 0};
#pragma unroll
        for (int k2 = 0; k2 < 8; ++k2)
          sum += *(const f32x4*)&part[((k2 << 6) + rm) * 36 + rng];
        float h0 = tanhf(sum[0] + qb[0]);
        float h1 = tanhf(sum[1] + qb[1]);
        float h2 = tanhf(sum[2] + qb[2]);
        float h3 = tanhf(sum[3] + qb[3]);
        size_t idx = ((size_t)l * BB + rm) * DD + qcol;
        u64 pk = (u64)f2b(h0) | ((u64)f2b(h1) << 16) |
                 ((u64)f2b(h2) << 32) | ((u64)f2b(h3) << 48);
        u64 val = (t < qlen) ? pk : *(const u64*)(Hp + idx);
        __hip_atomic_store((u64*)(Hc + idx), val, __ATOMIC_RELAXED,
                           __HIP_MEMORY_SCOPE_AGENT);
      }
      asm volatile("s_waitcnt vmcnt(0)" ::: "memory");
    }
    __syncthreads();

    const int ep = t + 1;
    if (t < TT && tid == 0)
      __hip_atomic_store(&flags[bid << 5], ep, __ATOMIC_RELAXED,
                         __HIP_MEMORY_SCOPE_AGENT);

    // out-proj for step t-1 (Hp; all 64 rows — frozen rows valid in every
    // buffer), overlapped with other blocks' arrivals
    if (t > 0) {
      const u16* h3p = Hp + (size_t)3 * BB * DD;
      const u16* hp = h3p + (size_t)opb * DD + (ln32 << 6);
      const u16* wp = WoT + (size_t)opv * DD + (ln32 << 6);
      float sacc = 0.f;
#pragma unroll
      for (int j = 0; j < 64; j += 8) {
        s16x8 hv8 = *(const s16x8*)(hp + j);
        s16x8 wv8 = *(const s16x8*)(wp + j);
#pragma unroll
        for (int e = 0; e < 8; ++e)
          sacc = fmaf(b2f((u16)hv8[e]), b2f((u16)wv8[e]), sacc);
      }
#pragma unroll
      for (int d = 16; d > 0; d >>= 1) sacc += __shfl_xor(sacc, d, 64);
      if (ln32 == 0)
        out[((size_t)pbr * TT + (t - 1)) * VV + opv] = sacc + boutv;
    }

    if (t < TT) {
      for (;;) {   // HOT spin (R15)
        int f = ep;
        if (lane < 32)
          f = __hip_atomic_load(&flags[fidx], __ATOMIC_RELAXED,
                                __HIP_MEMORY_SCOPE_AGENT);
        int ok = __all(f - ep >= 0);
        if (lane == 0) wok[w] = ok;
        __syncthreads();
        if (tid == 0)
          alldone = wok[0] & wok[1] & wok[2] & wok[3] &
                    wok[4] & wok[5] & wok[6] & wok[7];
        __syncthreads();
        if (alldone) break;
      }
      if ((ep & 3) == 0 && tid == 0)
        __hip_atomic_load(&flags[0], __ATOMIC_ACQUIRE, __HIP_MEMORY_SCOPE_AGENT);
      __syncthreads();
    }
  }
}

extern "C" void kernel_launch(void* const* d_in, const int* in_sizes, int n_in,
                              void* d_out, int out_size, void* d_ws, size_t ws_size,
                              hipStream_t stream) {
  const int* ids = (const int*)d_in[0];
  const int* slen = (const int*)d_in[1];
  const float* emb = (const float*)d_in[2];
  const float* Wx = (const float*)d_in[3];
  const float* bx = (const float*)d_in[4];
  const float* Wh = (const float*)d_in[5];
  const float* bh = (const float*)d_in[6];
  const float* Wout = (const float*)d_in[7];
  const float* bout = (const float*)d_in[8];
  float* out = (float*)d_out;

  char* ws = (char*)d_ws;
  const size_t oW = (size_t)LL * DD * DD * 2;
  const size_t oWoT = (size_t)VV * DD * 2;
  const size_t oEmb = (size_t)VV * DD * 2;
  const size_t oHb = (size_t)LL * BB * DD * 2;
  u16* Wxb = (u16*)ws;
  u16* Whb = (u16*)(ws + oW);
  u16* WoT = (u16*)(ws + 2 * oW);
  u16* embb = (u16*)(ws + 2 * oW + oWoT);
  u16* hb = (u16*)(ws + 2 * oW + oWoT + oEmb);          // 4-ring state
  char* base = ws + 2 * oW + oWoT + oEmb + 4 * oHb;
  int* flags = (int*)base;                               // 32768 B
  int* idsT = (int*)(base + 32768);                      // 131072 B
  int* perm = (int*)(base + 32768 + 131072);             // 256 B
  int* slenP = (int*)(base + 32768 + 131072 + 256);      // 256 B
  int* nact = (int*)(base + 32768 + 131072 + 512);       // 2048 B

  hipMemsetAsync(ws + 2 * oW + oWoT + oEmb, 0, 4 * oHb + 32768, stream);

  const size_t n4 = (size_t)LL * DD * DD / 4;
  convert_w<<<dim3(4096), dim3(256), 0, stream>>>(Wx, Wxb, n4);
  convert_w<<<dim3(4096), dim3(256), 0, stream>>>(Wh, Whb, n4);
  convert_w<<<dim3(128), dim3(256), 0, stream>>>(emb, embb, (size_t)VV * DD / 4);
  convert_woT<<<dim3(512), dim3(256), 0, stream>>>(Wout, WoT);
  prep64<<<dim3(1), dim3(64), 0, stream>>>(slen, perm, slenP, nact);
  transpose_ids_p<<<dim3(128), dim3(256), 0, stream>>>(ids, perm, idsT);

  void* kp[14];
  kp[0] = (void*)&idsT; kp[1] = (void*)&slenP;
  kp[2] = (void*)&bx;   kp[3] = (void*)&bh;   kp[4] = (void*)&embb;
  kp[5] = (void*)&Wxb;  kp[6] = (void*)&Whb;  kp[7] = (void*)&WoT;
  kp[8] = (void*)&bout; kp[9] = (void*)&hb;   kp[10] = (void*)&out;
  kp[11] = (void*)&flags; kp[12] = (void*)&perm; kp[13] = (void*)&nact;
  hipLaunchCooperativeKernel((const void*)persist, dim3(256), dim3(512), kp, 0, stream);
}

// Round 17
// 5497.938 us; speedup vs baseline: 1.4993x; 1.0340x over previous
//
#include <hip/hip_runtime.h>
#include <hip/hip_bf16.h>

#define TT 512
#define BB 64
#define DD 2048
#define LL 4
#define VV 64

typedef unsigned short u16;
typedef unsigned int u32;
typedef unsigned long long u64;
typedef __attribute__((ext_vector_type(8))) short s16x8;
typedef __attribute__((ext_vector_type(4))) float f32x4;

#define MFMA(a, b, c) __builtin_amdgcn_mfma_f32_16x16x32_bf16((a), (b), (c), 0, 0, 0)

#define GL(gp, lp)                                                        \
  __builtin_amdgcn_global_load_lds(                                       \
      (const __attribute__((address_space(1))) void*)(gp),                \
      (__attribute__((address_space(3))) void*)(lp), 16, 0, 0)

__device__ inline u16 f2b(float f) {
  u32 u = __builtin_bit_cast(u32, f);
  u32 r = (u + 0x7fffu + ((u >> 16) & 1u)) >> 16;
  return (u16)r;
}
__device__ inline float b2f(u16 b) {
  u32 u = ((u32)b) << 16;
  return __builtin_bit_cast(float, u);
}

__global__ __launch_bounds__(256) void convert_w(const float* __restrict__ src,
                                                 u16* __restrict__ dst, size_t n4) {
  size_t i = (size_t)blockIdx.x * 256 + threadIdx.x;
  size_t stride = (size_t)gridDim.x * 256;
  for (size_t j = i; j < n4; j += stride) {
    float4 f = ((const float4*)src)[j];
    ushort4 o;
    o.x = f2b(f.x); o.y = f2b(f.y); o.z = f2b(f.z); o.w = f2b(f.w);
    ((ushort4*)dst)[j] = o;
  }
}

__global__ __launch_bounds__(256) void convert_woT(const float* __restrict__ Wout,
                                                   u16* __restrict__ WoT) {
  int g = blockIdx.x * 256 + threadIdx.x;
  int v = g >> 11, k = g & 2047;
  WoT[(size_t)v * DD + k] = f2b(Wout[(size_t)k * VV + v]);
}

// stable rank-sort of 64 rows by descending slen; nact[t] = #{slen+4 > t}
__global__ __launch_bounds__(64) void prep64(const int* __restrict__ slen,
                                             int* __restrict__ perm,
                                             int* __restrict__ slenP,
                                             int* __restrict__ nact) {
  __shared__ int sperm[64];
  const int b = threadIdx.x;
  const int s = slen[b];
  int r = 0;
  for (int j = 0; j < 64; ++j) {
    int sj = slen[j];
    r += (sj > s) || ((sj == s) && (j < b));
  }
  sperm[r] = b;
  __syncthreads();
  perm[b] = sperm[b];
  slenP[b] = slen[sperm[b]];
  for (int t = b; t < TT; t += 64) {
    int c = 0;
    for (int j = 0; j < 64; ++j) c += (slen[j] + 4 > t) ? 1 : 0;
    nact[t] = c;
  }
}

// idsT[t][j] = ids[perm[j]][t]
__global__ __launch_bounds__(256) void transpose_ids_p(const int* __restrict__ ids,
                                                       const int* __restrict__ perm,
                                                       int* __restrict__ idsT) {
  int g = blockIdx.x * 256 + threadIdx.x;  // 32768
  int t = g >> 6, j = g & 63;
  idsT[t * BB + j] = ids[perm[j] * TT + t];
}

// Persistent: 256 blocks x 512 threads, 1 block/CU. Block -> (layer, 32 cols).
// R16 structure + EXACT-ROW activity granularity: GL issues are exec-masked
// per lane (row < nact) so frozen boundary-group rows stage nothing (their
// stale LDS feeds MFMA rows whose results are discarded: rows >= nact have
// t >= slen+4, already carry-written into all 4 ring buffers, so their store
// is skipped too). vmcnt ladder unchanged (each r<ng GL still issues once
// per wave). sids double-buffered: ids(t+1) loaded BEFORE the staging
// prologue (drains first in the vmcnt queue), published before the post-
// store sync -> layer-0's serial ids load + extra barrier removed.
__global__ __launch_bounds__(512, 2)
void persist(const int* __restrict__ idsT, const int* __restrict__ slenP,
             const float* __restrict__ bxp, const float* __restrict__ bhp,
             const u16* __restrict__ embb,
             const u16* __restrict__ Wxb, const u16* __restrict__ Whb,
             const u16* __restrict__ WoT, const float* __restrict__ bout,
             u16* hb, float* __restrict__ out, int* flags,
             const int* __restrict__ perm, const int* __restrict__ nact) {
  const int tid = threadIdx.x, bid = blockIdx.x;
  const int l = bid >> 6;
  const int col0 = (bid & 63) << 5;
  const int w = tid >> 6, lane = tid & 63;
  const int lr = lane & 15, q = lane >> 4;
  const size_t HSZ = (size_t)LL * BB * DD;

  // ---- weight frags: [ctile][chunk], k = w*256 + j*32 + q*8 ----
  s16x8 wx[2][8], wh[2][8];
#pragma unroll
  for (int c = 0; c < 2; ++c) {
    const int ncol = col0 + (c << 4) + lr;
    const u16* p0 = Wxb + ((size_t)l * DD + ncol) * DD + (w << 8) + (q << 3);
    const u16* p1 = Whb + ((size_t)l * DD + ncol) * DD + (w << 8) + (q << 3);
#pragma unroll
    for (int j = 0; j < 8; ++j) {
      wx[c][j] = *(const s16x8*)(p0 + (j << 5));
      wh[c][j] = *(const s16x8*)(p1 + (j << 5));
    }
  }
#pragma unroll
  for (int c = 0; c < 2; ++c)
#pragma unroll
    for (int j = 0; j < 8; ++j) {
      asm("" : "+v"(wx[c][j]));
      asm("" : "+v"(wh[c][j]));
    }

  // ---- out-proj: 4 batch x 4 vocab per block (perm'd output row) ----
  const int opo = tid >> 5, ln32 = tid & 31;
  const int opb = ((bid >> 4) << 2) + (opo >> 2);
  const int opv = ((bid & 15) << 2) + (opo & 3);
  const int pbr = perm[opb];
  const float boutv = bout[opv];

  // ---- reduce mapping: thread -> (row, col-quad) ----
  const int rm = tid >> 3;
  const int rng = (tid & 7) << 2;
  const int qcol = col0 + rng;
  float qb[4];
#pragma unroll
  for (int e = 0; e < 4; ++e)
    qb[e] = bxp[l * DD + qcol + e] + bhp[l * DD + qcol + e];
  const int qlen = slenP[rm];

  // ---- staging lane decomposition (source pre-permuted; rule #21) ----
  const int lrow = lane >> 2;
  const int lelem = ((lane & 3) ^ ((lane >> 3) & 3)) << 3;
  const int fx = lr * 32 + ((q ^ ((lr >> 1) & 3)) << 3);

  const int fidx = ((w << 5) + (lane & 31)) << 5;  // barrier scan flag

  // LDS: stg (8 waves x 2 slots x 8KB = 128KB) UNION part[8][64][36] (72KB)
  __shared__ __align__(16) u16 stg[65536];
  float* part = (float*)stg;
  __shared__ int sids[2][64];
  __shared__ int wok[8];
  __shared__ int alldone;

  u16* wslot = stg + (w << 13);

  // preload ids for t=0
  if (l == 0 && tid < BB) sids[0][tid] = idsT[tid];
  __syncthreads();

  for (int t = 0; t <= TT; ++t) {
    const u16* Hp = hb + (size_t)((t + 3) & 3) * HSZ;
    u16* Hc = hb + (size_t)(t & 3) * HSZ;

    if (t < TT) {
      const int nactT = nact[t];
      const int ng = (nactT + 15) >> 4;  // active row-groups (0..4), uniform
      const int tn = t + 1;

      // ids(t+1) load BEFORE staging prologue: oldest in vmcnt queue
      int nid = 0;
      if (l == 0 && tn < TT && tid < BB) nid = idsT[tn * BB + tid];

      const int kw = (w << 8) + lelem;
      const u16* hb0 = Hp + (size_t)l * BB * DD + kw;
      const u16* px[4];
      const u16* ph[4];
      if (l == 0) {
        const int* sc = sids[t & 1];
        px[0] = embb + (size_t)sc[lrow] * DD + kw;
        px[1] = embb + (size_t)sc[16 + lrow] * DD + kw;
        px[2] = embb + (size_t)sc[32 + lrow] * DD + kw;
        px[3] = embb + (size_t)sc[48 + lrow] * DD + kw;
      } else {
        const u16* xb0 = Hp + (size_t)(l - 1) * BB * DD + kw;
        px[0] = xb0 + (size_t)lrow * DD;
        px[1] = xb0 + (size_t)(16 + lrow) * DD;
        px[2] = xb0 + (size_t)(32 + lrow) * DD;
        px[3] = xb0 + (size_t)(48 + lrow) * DD;
      }
      ph[0] = hb0 + (size_t)lrow * DD;
      ph[1] = hb0 + (size_t)(16 + lrow) * DD;
      ph[2] = hb0 + (size_t)(32 + lrow) * DD;
      ph[3] = hb0 + (size_t)(48 + lrow) * DD;

      // prologue: stage chunks 0,1 (2*ng GL instrs each; frozen lanes masked)
#pragma unroll
      for (int c = 0; c < 2; ++c) {
        u16* d = wslot + (c << 12);
#pragma unroll
        for (int r = 0; r < 4; ++r)
          if (r < ng && ((r << 4) | lrow) < nactT) {
            GL(px[r] + (c << 5), d + (r << 9));
            GL(ph[r] + (c << 5), d + 2048 + (r << 9));
          }
      }

      f32x4 acc[2][4] = {{{0,0,0,0},{0,0,0,0},{0,0,0,0},{0,0,0,0}},
                         {{0,0,0,0},{0,0,0,0},{0,0,0,0},{0,0,0,0}}};
#pragma unroll
      for (int j = 0; j < 8; ++j) {
        if (j < 7) {  // one chunk (2*ng instrs) may remain outstanding
          if (ng == 4)      asm volatile("s_waitcnt vmcnt(8)" ::: "memory");
          else if (ng == 3) asm volatile("s_waitcnt vmcnt(6)" ::: "memory");
          else if (ng == 2) asm volatile("s_waitcnt vmcnt(4)" ::: "memory");
          else              asm volatile("s_waitcnt vmcnt(2)" ::: "memory");
        } else {
          asm volatile("s_waitcnt vmcnt(0)" ::: "memory");
        }
        __builtin_amdgcn_sched_barrier(0);
        const u16* sb = wslot + ((j & 1) << 12);
        s16x8 ax[4], ah[4];
#pragma unroll
        for (int r = 0; r < 4; ++r)
          if (r < ng) {
            ax[r] = *(const s16x8*)(sb + (r << 9) + fx);
            ah[r] = *(const s16x8*)(sb + 2048 + (r << 9) + fx);
          }
        asm volatile("s_waitcnt lgkmcnt(0)" ::: "memory");
        __builtin_amdgcn_sched_barrier(0);
        if (j < 6) {  // refill same slot with chunk j+2 (reads done)
          u16* d = wslot + ((j & 1) << 12);
          const int co = (j + 2) << 5;
#pragma unroll
          for (int r = 0; r < 4; ++r)
            if (r < ng && ((r << 4) | lrow) < nactT) {
              GL(px[r] + co, d + (r << 9));
              GL(ph[r] + co, d + 2048 + (r << 9));
            }
        }
#pragma unroll
        for (int c = 0; c < 2; ++c)
#pragma unroll
          for (int r = 0; r < 4; ++r)
            if (r < ng) {
              acc[c][r] = MFMA(ax[r], wx[c][j], acc[c][r]);
              acc[c][r] = MFMA(ah[r], wh[c][j], acc[c][r]);
            }
      }

      __syncthreads();  // all waves done reading stg; part may overwrite
#pragma unroll
      for (int c = 0; c < 2; ++c)
#pragma unroll
        for (int mt = 0; mt < 4; ++mt)
          if (mt < ng)
#pragma unroll
            for (int i = 0; i < 4; ++i)
              part[((w << 6) + (mt << 4) + (q << 2) + i) * 36 + (c << 4) + lr] =
                  acc[c][mt][i];
      __syncthreads();

      // 8-way K-combine + bias + tanh + mask + packed agent write-through
      // store — EXACT rows only (rows >= nact already carry-written 4x)
      if (rm < nactT) {
        f32x4 sum = {0, 0, 0, 0};
#pragma unroll
        for (int k2 = 0; k2 < 8; ++k2)
          sum += *(const f32x4*)&part[((k2 << 6) + rm) * 36 + rng];
        float h0 = tanhf(sum[0] + qb[0]);
        float h1 = tanhf(sum[1] + qb[1]);
        float h2 = tanhf(sum[2] + qb[2]);
        float h3 = tanhf(sum[3] + qb[3]);
        size_t idx = ((size_t)l * BB + rm) * DD + qcol;
        u64 pk = (u64)f2b(h0) | ((u64)f2b(h1) << 16) |
                 ((u64)f2b(h2) << 32) | ((u64)f2b(h3) << 48);
        u64 val = (t < qlen) ? pk : *(const u64*)(Hp + idx);
        __hip_atomic_store((u64*)(Hc + idx), val, __ATOMIC_RELAXED,
                           __HIP_MEMORY_SCOPE_AGENT);
      }
      // publish ids(t+1); ordered for next step by the syncthreads below
      if (l == 0 && tn < TT && tid < BB) sids[tn & 1][tid] = nid;
      asm volatile("s_waitcnt vmcnt(0)" ::: "memory");
    }
    __syncthreads();

    const int ep = t + 1;
    if (t < TT && tid == 0)
      __hip_atomic_store(&flags[bid << 5], ep, __ATOMIC_RELAXED,
                         __HIP_MEMORY_SCOPE_AGENT);

    // out-proj for step t-1 (Hp; frozen rows valid in every buffer),
    // overlapped with other blocks' arrivals
    if (t > 0) {
      const u16* h3p = Hp + (size_t)3 * BB * DD;
      const u16* hp = h3p + (size_t)opb * DD + (ln32 << 6);
      const u16* wp = WoT + (size_t)opv * DD + (ln32 << 6);
      float sacc = 0.f;
#pragma unroll
      for (int j = 0; j < 64; j += 8) {
        s16x8 hv8 = *(const s16x8*)(hp + j);
        s16x8 wv8 = *(const s16x8*)(wp + j);
#pragma unroll
        for (int e = 0; e < 8; ++e)
          sacc = fmaf(b2f((u16)hv8[e]), b2f((u16)wv8[e]), sacc);
      }
#pragma unroll
      for (int d = 16; d > 0; d >>= 1) sacc += __shfl_xor(sacc, d, 64);
      if (ln32 == 0)
        out[((size_t)pbr * TT + (t - 1)) * VV + opv] = sacc + boutv;
    }

    if (t < TT) {
      for (;;) {   // HOT spin (R15)
        int f = ep;
        if (lane < 32)
          f = __hip_atomic_load(&flags[fidx], __ATOMIC_RELAXED,
                                __HIP_MEMORY_SCOPE_AGENT);
        int ok = __all(f - ep >= 0);
        if (lane == 0) wok[w] = ok;
        __syncthreads();
        if (tid == 0)
          alldone = wok[0] & wok[1] & wok[2] & wok[3] &
                    wok[4] & wok[5] & wok[6] & wok[7];
        __syncthreads();
        if (alldone) break;
      }
      if ((ep & 3) == 0 && tid == 0)
        __hip_atomic_load(&flags[0], __ATOMIC_ACQUIRE, __HIP_MEMORY_SCOPE_AGENT);
      __syncthreads();
    }
  }
}

extern "C" void kernel_launch(void* const* d_in, const int* in_sizes, int n_in,
                              void* d_out, int out_size, void* d_ws, size_t ws_size,
                              hipStream_t stream) {
  const int* ids = (const int*)d_in[0];
  const int* slen = (const int*)d_in[1];
  const float* emb = (const float*)d_in[2];
  const float* Wx = (const float*)d_in[3];
  const float* bx = (const float*)d_in[4];
  const float* Wh = (const float*)d_in[5];
  const float* bh = (const float*)d_in[6];
  const float* Wout = (const float*)d_in[7];
  const float* bout = (const float*)d_in[8];
  float* out = (float*)d_out;

  char* ws = (char*)d_ws;
  const size_t oW = (size_t)LL * DD * DD * 2;
  const size_t oWoT = (size_t)VV * DD * 2;
  const size_t oEmb = (size_t)VV * DD * 2;
  const size_t oHb = (size_t)LL * BB * DD * 2;
  u16* Wxb = (u16*)ws;
  u16* Whb = (u16*)(ws + oW);
  u16* WoT = (u16*)(ws + 2 * oW);
  u16* embb = (u16*)(ws + 2 * oW + oWoT);
  u16* hb = (u16*)(ws + 2 * oW + oWoT + oEmb);          // 4-ring state
  char* base = ws + 2 * oW + oWoT + oEmb + 4 * oHb;
  int* flags = (int*)base;                               // 32768 B
  int* idsT = (int*)(base + 32768);                      // 131072 B
  int* perm = (int*)(base + 32768 + 131072);             // 256 B
  int* slenP = (int*)(base + 32768 + 131072 + 256);      // 256 B
  int* nact = (int*)(base + 32768 + 131072 + 512);       // 2048 B

  hipMemsetAsync(ws + 2 * oW + oWoT + oEmb, 0, 4 * oHb + 32768, stream);

  const size_t n4 = (size_t)LL * DD * DD / 4;
  convert_w<<<dim3(4096), dim3(256), 0, stream>>>(Wx, Wxb, n4);
  convert_w<<<dim3(4096), dim3(256), 0, stream>>>(Wh, Whb, n4);
  convert_w<<<dim3(128), dim3(256), 0, stream>>>(emb, embb, (size_t)VV * DD / 4);
  convert_woT<<<dim3(512), dim3(256), 0, stream>>>(Wout, WoT);
  prep64<<<dim3(1), dim3(64), 0, stream>>>(slen, perm, slenP, nact);
  transpose_ids_p<<<dim3(128), dim3(256), 0, stream>>>(ids, perm, idsT);

  void* kp[14];
  kp[0] = (void*)&idsT; kp[1] = (void*)&slenP;
  kp[2] = (void*)&bx;   kp[3] = (void*)&bh;   kp[4] = (void*)&embb;
  kp[5] = (void*)&Wxb;  kp[6] = (void*)&Whb;  kp[7] = (void*)&WoT;
  kp[8] = (void*)&bout; kp[9] = (void*)&hb;   kp[10] = (void*)&out;
  kp[11] = (void*)&flags; kp[12] = (void*)&perm; kp[13] = (void*)&nact;
  hipLaunchCooperativeKernel((const void*)persist, dim3(256), dim3(512), kp, 0, stream);
}